// Round 11
// baseline (151.024 us; speedup 1.0000x reference)
//
#include <hip/hip_runtime.h>
#include <hip/hip_bf16.h>
#include <cmath>

#define NN 4096    // H*W
typedef __attribute__((ext_vector_type(8))) short short8;
typedef __attribute__((ext_vector_type(4))) float f32x4;

__device__ __forceinline__ float bf2f(unsigned short u) {
  union { unsigned int i; float f; } c; c.i = ((unsigned int)u) << 16; return c.f;
}

// ---------------------------------------------------------------------------
// weight prep, coalesced reads (c contiguous per k-row), scattered bf16 writes
//   wcatT[c][k] c<256: qkv_w[k][512+c]; c<320: off_w[k][c-256];
//               c<352: attw_w[k][c-320]; else 0
//   pjT[c][k] = proj_w[k][c]
// ---------------------------------------------------------------------------
__global__ __launch_bounds__(256) void cvt_w(
    const float* __restrict__ qkv_w, const float* __restrict__ off_w,
    const float* __restrict__ attw_w, const float* __restrict__ proj_w,
    __hip_bfloat16* __restrict__ wcatT, __hip_bfloat16* __restrict__ pjT)
{
  const int t = threadIdx.x;
  if (blockIdx.x < 256) {
    int k = blockIdx.x;
    wcatT[t * 256 + k] = __float2bfloat16(qkv_w[k * 768 + 512 + t]);
    if (t < 128) {
      int c2 = 256 + t;
      float v = 0.f;
      if (c2 < 320)      v = off_w[k * 64 + (c2 - 256)];
      else if (c2 < 352) v = attw_w[k * 32 + (c2 - 320)];
      wcatT[c2 * 256 + k] = __float2bfloat16(v);
    }
  } else {
    int k = blockIdx.x - 256;
    pjT[t * 256 + k] = __float2bfloat16(proj_w[k * 256 + t]);
  }
}

// ---------------------------------------------------------------------------
// fused v-GEMM + offset/attention logits + COMPACT sampling-table epilogue.
// R7-proven shape: 512 threads (8 waves, 2x4), tile 128 rows x 384 cols,
// grid 256, XCD-chunked swizzle, 32 B/pair compact table.
// NEW vs R7: TRANSPOSED-ACC epilogue — mfma(b, a) so each lane holds
// (m-row = lane&15, 4 consecutive n-cols = (lane>>4)*4+r). v writes become
// 8 B dwordx2, logit writes become one aligned float4 to LDS. 4x fewer
// store instructions; MFMA count and staging unchanged.
// ---------------------------------------------------------------------------
__global__ __launch_bounds__(512) void gemm_voff(
    const float* __restrict__ x,
    const __hip_bfloat16* __restrict__ wcatT,
    const float* __restrict__ vbias,
    const float* __restrict__ off_b, const float* __restrict__ attw_b,
    __hip_bfloat16* __restrict__ vb,
    unsigned int* __restrict__ table)
{
  __shared__ float smemf[12800];              // 51200 B
  short* As = (short*)smemf;                  // 128 * 40 shorts = 10240 B
  short* Bs = As + 128 * 40;                  // 384 * 40 shorts = 30720 B
  float (*L)[100] = (float(*)[100])smemf;     // aliased AFTER the K loop

  const int t = threadIdx.x;
  const int bid = blockIdx.x;
  // 256 blocks = 8 XCD chunks x 32 tiles; chunk k == batch k
  const int m0 = (((bid & 7) << 5) | (bid >> 3)) * 128;
  const int wave = t >> 6, lane = t & 63, q = lane >> 4, ln = lane & 15;
  const int wm = (wave & 1) * 64, wn = (wave >> 1) * 96;

  f32x4 acc[4][6] = {};

  const int arow = t >> 2, aseg = t & 3;          // A staging: 128 rows x 4 segs
  const float* apg = x + (size_t)(m0 + arow) * 256 + aseg * 8;

  for (int k0 = 0; k0 < 256; k0 += 32) {
    // A: 128x32 fp32 -> bf16
    float4 f0 = *(const float4*)(apg + k0);
    float4 f1 = *(const float4*)(apg + k0 + 4);
    alignas(16) __hip_bfloat16 cv[8] = {
      __float2bfloat16(f0.x), __float2bfloat16(f0.y), __float2bfloat16(f0.z), __float2bfloat16(f0.w),
      __float2bfloat16(f1.x), __float2bfloat16(f1.y), __float2bfloat16(f1.z), __float2bfloat16(f1.w)};
    *(int4*)&As[arow * 40 + aseg * 8] = *(int4*)cv;
    // B: 384x32 bf16, 1536 16B units / 512 thr = 3 each
#pragma unroll
    for (int i = 0; i < 3; ++i) {
      int u = t + i * 512;
      int brow = u >> 2, bseg = u & 3;
      *(int4*)&Bs[brow * 40 + bseg * 8] =
          *(const int4*)&wcatT[(size_t)brow * 256 + k0 + bseg * 8];
    }
    __syncthreads();
    short8 a[4], b[6];
#pragma unroll
    for (int i = 0; i < 4; ++i) a[i] = *(const short8*)&As[(wm + i * 16 + ln) * 40 + q * 8];
#pragma unroll
    for (int j = 0; j < 6; ++j) b[j] = *(const short8*)&Bs[(wn + j * 16 + ln) * 40 + q * 8];
#pragma unroll
    for (int i = 0; i < 4; ++i)
#pragma unroll
      for (int j = 0; j < 6; ++j)
        acc[i][j] = __builtin_amdgcn_mfma_f32_16x16x32_bf16(b[j], a[i], acc[i][j], 0, 0, 0);
    __syncthreads();
  }

  // transposed-acc epilogue: lane (q,ln) reg r holds C[m=ln(+tile)][n=quad q*4+r]
#pragma unroll
  for (int j = 0; j < 6; ++j) {
    int colb = wn + j * 16 + q * 4;          // n-quad base, multiple of 4
    if (colb < 256) {
      float4 bv = *(const float4*)&vbias[colb];
#pragma unroll
      for (int i = 0; i < 4; ++i) {
        int row = m0 + wm + i * 16 + ln;
        alignas(8) __hip_bfloat16 o[4] = {
          __float2bfloat16(acc[i][j][0] + bv.x),
          __float2bfloat16(acc[i][j][1] + bv.y),
          __float2bfloat16(acc[i][j][2] + bv.z),
          __float2bfloat16(acc[i][j][3] + bv.w)};
        *(uint2*)&vb[(size_t)row * 256 + colb] = *(uint2*)o;
      }
    } else if (colb < 352) {
      int lcb = colb - 256;                  // [0,96), multiple of 4
      float4 bv = (lcb < 64) ? *(const float4*)&off_b[lcb]
                             : *(const float4*)&attw_b[lcb - 64];
#pragma unroll
      for (int i = 0; i < 4; ++i) {
        int rr = wm + i * 16 + ln;
        float4 o = {acc[i][j][0] + bv.x, acc[i][j][1] + bv.y,
                    acc[i][j][2] + bv.z, acc[i][j][3] + bv.w};
        *(float4*)&L[rr][lcb] = o;
      }
    }
  }
  __syncthreads();

  // compact table epilogue: 1024 (row,head) pairs, 2 per thread, 24 B each
#pragma unroll
  for (int it = 0; it < 2; ++it) {
    int pl = t + it * 512;
    int rr = pl >> 3, h = pl & 7;
    int row = m0 + rr;

    float a0 = L[rr][64 + h * 4 + 0], a1 = L[rr][64 + h * 4 + 1];
    float a2 = L[rr][64 + h * 4 + 2], a3 = L[rr][64 + h * 4 + 3];
    float mx = fmaxf(fmaxf(a0, a1), fmaxf(a2, a3));
    float e0 = expf(a0 - mx), e1 = expf(a1 - mx), e2 = expf(a2 - mx), e3 = expf(a3 - mx);
    float inv = 1.f / (e0 + e1 + e2 + e3);

    alignas(16) _Float16 pk[12];
#pragma unroll
    for (int p = 0; p < 4; ++p) {
      pk[p * 2 + 0] = (_Float16)(2.f * tanhf(L[rr][h * 8 + p * 2 + 0]));
      pk[p * 2 + 1] = (_Float16)(2.f * tanhf(L[rr][h * 8 + p * 2 + 1]));
    }
    pk[8]  = (_Float16)(e0 * inv);
    pk[9]  = (_Float16)(e1 * inv);
    pk[10] = (_Float16)(e2 * inv);
    pk[11] = (_Float16)(e3 * inv);

    size_t pg = (size_t)row * 8 + h;
    *(uint4*)(table + pg * 8)     = *(uint4*)&pk[0];   // 16 B: dx,dy x4
    *(uint2*)(table + pg * 8 + 4) = *(uint2*)&pk[8];   //  8 B: attn x4
  }
}

// ---------------------------------------------------------------------------
// sampler: thread = (pair, 8-channel group). 64 pairs/block, compact 32 B
// table entries staged in LDS; corners recomputed in-register. Gathers are
// 16B dwordx4 from v. XCD-chunked swizzle: chunk k == batch k on XCD k.
// (unchanged from R7)
// ---------------------------------------------------------------------------
__global__ __launch_bounds__(256) void sample_kernel(
    const __hip_bfloat16* __restrict__ v,
    const unsigned int* __restrict__ table,
    __hip_bfloat16* __restrict__ y)
{
  __shared__ uint4 Tab[128];                 // 64 pairs x 32 B
  const int t = threadIdx.x;
  const int bid = blockIdx.x;
  const int p0 = (((bid & 7) << 9) | (bid >> 3)) * 64;   // batch k on XCD k
  if (t < 128) Tab[t] = *(const uint4*)(table + (size_t)p0 * 8 + t * 4);
  __syncthreads();

  const int g = t & 3, p = t >> 2;
  const int pg = p0 + p;
  const int h = pg & 7;
  const int row = pg >> 3;                   // [0, 32768)
  const int b = row >> 12;
  const int nl = row & (NN - 1);
  const float refx = (float)(nl & 63);
  const float refy = (float)(nl >> 6);

  const _Float16* dp  = (const _Float16*)&Tab[p * 2];      // dx,dy x4
  const _Float16* ap_ = (const _Float16*)&Tab[p * 2 + 1];  // attn x4

  alignas(16) unsigned short idxs[16];
  float ws[16];
#pragma unroll
  for (int pp = 0; pp < 4; ++pp) {
    float gx = refx + (float)dp[2 * pp + 0];
    float gy = refy + (float)dp[2 * pp + 1];
    float x0f = floorf(gx), y0f = floorf(gy);
    int x0 = (int)x0f, y0 = (int)y0f;
    int x1 = x0 + 1,   y1 = y0 + 1;
    float wx1 = gx - x0f, wx0 = 1.f - wx1;
    float wy1 = gy - y0f, wy0 = 1.f - wy1;
    int cx0 = min(max(x0, 0), 63), cx1 = min(max(x1, 0), 63);
    int cy0 = min(max(y0, 0), 63), cy1 = min(max(y1, 0), 63);
    float vx0 = (x0 >= 0 && x0 <= 63) ? 1.f : 0.f;
    float vx1 = (x1 >= 0 && x1 <= 63) ? 1.f : 0.f;
    float vy0 = (y0 >= 0 && y0 <= 63) ? 1.f : 0.f;
    float vy1 = (y1 >= 0 && y1 <= 63) ? 1.f : 0.f;
    float apv = (float)ap_[pp];
    idxs[pp * 4 + 0] = (unsigned short)(cy0 * 64 + cx0);
    idxs[pp * 4 + 1] = (unsigned short)(cy0 * 64 + cx1);
    idxs[pp * 4 + 2] = (unsigned short)(cy1 * 64 + cx0);
    idxs[pp * 4 + 3] = (unsigned short)(cy1 * 64 + cx1);
    ws[pp * 4 + 0] = apv * wx0 * wy0 * vx0 * vy0;
    ws[pp * 4 + 1] = apv * wx1 * wy0 * vx1 * vy0;
    ws[pp * 4 + 2] = apv * wx0 * wy1 * vx0 * vy1;
    ws[pp * 4 + 3] = apv * wx1 * wy1 * vx1 * vy1;
  }

  const char* vbase = (const char*)(v + (size_t)b * NN * 256 + h * 32 + g * 8);

  float acc[8] = {};
#pragma unroll
  for (int j = 0; j < 16; ++j) {
    float w = ws[j];
    int idx = idxs[j];
    int4 pk = *(const int4*)(vbase + (size_t)idx * 512);
    const unsigned short* u = (const unsigned short*)&pk;
#pragma unroll
    for (int c = 0; c < 8; ++c) acc[c] += w * bf2f(u[c]);
  }
  alignas(16) __hip_bfloat16 o[8];
#pragma unroll
  for (int c = 0; c < 8; ++c) o[c] = __float2bfloat16(acc[c]);
  *(int4*)((char*)y + ((size_t)row * 256 + h * 32 + g * 8) * 2) = *(int4*)o;
}

// ---------------------------------------------------------------------------
// proj GEMM: out[M,256] = yb @ pjT^T + proj_b, fp32 out. 64x256 tile, yb
// read once, grid 512 XCD-chunked. NEW vs R7: transposed-acc epilogue —
// mfma(b, a) so the four acc values per (i,j) are 4 consecutive out cols:
// one float4 store instead of 4 scalar stores.
// ---------------------------------------------------------------------------
__global__ __launch_bounds__(256) void gemm_proj(
    const short* __restrict__ A, const short* __restrict__ BT,
    const float* __restrict__ bias, float* __restrict__ out)
{
  __shared__ short As[64 * 40];              // 5120 B
  __shared__ short Bs[256 * 40];             // 20480 B
  const int t = threadIdx.x;
  const int bid = blockIdx.x;
  // 512 blocks = 8 chunks x 64 m-tiles; chunk k == batch k
  const int m0 = (((bid & 7) << 6) | (bid >> 3)) * 64;
  const int wave = t >> 6, lane = t & 63, q = lane >> 4, ln = lane & 15;
  const int wn = wave * 64;

  f32x4 acc[4][4] = {};

  const int arow = t >> 2, aseg = t & 3;     // A staging: 64 rows x 4 segs
  const short* apg = A + (size_t)(m0 + arow) * 256 + aseg * 8;

  for (int k0 = 0; k0 < 256; k0 += 32) {
    *(int4*)&As[arow * 40 + aseg * 8] = *(const int4*)(apg + k0);
    // B: 256x32 bf16, 1024 16B units / 256 thr = 4 each
#pragma unroll
    for (int u2 = 0; u2 < 4; ++u2) {
      int c = t + u2 * 256;
      int col = c >> 2, kq = c & 3;
      *(int4*)&Bs[col * 40 + kq * 8] =
          *(const int4*)&BT[(size_t)col * 256 + k0 + kq * 8];
    }
    __syncthreads();
    short8 a[4], b[4];
#pragma unroll
    for (int i = 0; i < 4; ++i) a[i] = *(const short8*)&As[(i * 16 + ln) * 40 + q * 8];
#pragma unroll
    for (int j = 0; j < 4; ++j) b[j] = *(const short8*)&Bs[(wn + j * 16 + ln) * 40 + q * 8];
#pragma unroll
    for (int i = 0; i < 4; ++i)
#pragma unroll
      for (int j = 0; j < 4; ++j)
        acc[i][j] = __builtin_amdgcn_mfma_f32_16x16x32_bf16(b[j], a[i], acc[i][j], 0, 0, 0);
    __syncthreads();
  }

#pragma unroll
  for (int j = 0; j < 4; ++j) {
    int colb = wn + j * 16 + q * 4;          // n-quad base
    float4 bv = *(const float4*)&bias[colb];
#pragma unroll
    for (int i = 0; i < 4; ++i) {
      int row = m0 + i * 16 + ln;
      float4 o = {acc[i][j][0] + bv.x, acc[i][j][1] + bv.y,
                  acc[i][j][2] + bv.z, acc[i][j][3] + bv.w};
      *(float4*)&out[(size_t)row * 256 + colb] = o;
    }
  }
}

// ---------------------------------------------------------------------------
extern "C" void kernel_launch(void* const* d_in, const int* in_sizes, int n_in,
                              void* d_out, int out_size, void* d_ws, size_t ws_size,
                              hipStream_t stream) {
  const float* x      = (const float*)d_in[0];
  const float* qkv_w  = (const float*)d_in[1];
  const float* qkv_b  = (const float*)d_in[2];
  const float* off_w  = (const float*)d_in[3];
  const float* off_b  = (const float*)d_in[4];
  const float* attw_w = (const float*)d_in[5];
  const float* attw_b = (const float*)d_in[6];
  const float* proj_w = (const float*)d_in[7];
  const float* proj_b = (const float*)d_in[8];
  float* out = (float*)d_out;

  char* ws = (char*)d_ws;
  __hip_bfloat16* vb    = (__hip_bfloat16*)(ws);                 // 16 MiB
  __hip_bfloat16* yb    = (__hip_bfloat16*)(ws + 16777216);      // 16 MiB
  unsigned int*   table = (unsigned int*)  (ws + 33554432);      // 8 MiB (compact)
  __hip_bfloat16* wcatT = (__hip_bfloat16*)(ws + 41943040);      // 192 KiB
  __hip_bfloat16* pjT   = (__hip_bfloat16*)(ws + 42139648);      // 128 KiB

  cvt_w<<<512, 256, 0, stream>>>(qkv_w, off_w, attw_w, proj_w, wcatT, pjT);
  gemm_voff<<<256, 512, 0, stream>>>(x, wcatT, qkv_b + 512, off_b, attw_b, vb, table);
  sample_kernel<<<4096, 256, 0, stream>>>(vb, table, yb);
  gemm_proj<<<512, 256, 0, stream>>>((const short*)yb, (const short*)pjT, proj_b, out);
}

// Round 14
// 143.096 us; speedup vs baseline: 1.0554x; 1.0554x over previous
//
#include <hip/hip_runtime.h>
#include <hip/hip_bf16.h>
#include <cmath>

#define NN 4096    // H*W
typedef __attribute__((ext_vector_type(8))) short short8;
typedef __attribute__((ext_vector_type(4))) float f32x4;

__device__ __forceinline__ float bf2f(unsigned short u) {
  union { unsigned int i; float f; } c; c.i = ((unsigned int)u) << 16; return c.f;
}

// ---------------------------------------------------------------------------
// weight prep, coalesced reads (c contiguous per k-row), scattered bf16 writes
//   wcatT[c][k] c<256: qkv_w[k][512+c]; c<320: off_w[k][c-256];
//               c<352: attw_w[k][c-320]; else 0
//   pjT[c][k] = proj_w[k][c]
// ---------------------------------------------------------------------------
__global__ __launch_bounds__(256) void cvt_w(
    const float* __restrict__ qkv_w, const float* __restrict__ off_w,
    const float* __restrict__ attw_w, const float* __restrict__ proj_w,
    __hip_bfloat16* __restrict__ wcatT, __hip_bfloat16* __restrict__ pjT)
{
  const int t = threadIdx.x;
  if (blockIdx.x < 256) {
    int k = blockIdx.x;
    wcatT[t * 256 + k] = __float2bfloat16(qkv_w[k * 768 + 512 + t]);
    if (t < 128) {
      int c2 = 256 + t;
      float v = 0.f;
      if (c2 < 320)      v = off_w[k * 64 + (c2 - 256)];
      else if (c2 < 352) v = attw_w[k * 32 + (c2 - 320)];
      wcatT[c2 * 256 + k] = __float2bfloat16(v);
    }
  } else {
    int k = blockIdx.x - 256;
    pjT[t * 256 + k] = __float2bfloat16(proj_w[k * 256 + t]);
  }
}

// ---------------------------------------------------------------------------
// fused v-GEMM + offset/attention logits + COMPACT sampling-table epilogue.
// R7-proven epilogues (REVERTED from R11's transposed-acc: it regressed
// 142.5 -> 151.0; worse store footprint, 16 lines/instr vs 4).
// NEW vs R7: single-barrier DOUBLE-BUFFERED K-loop with async-stage split —
// K-step k+1's global loads are issued before step k's ds_read+MFMA (they
// fly under compute), regs are written to the other LDS buffer after the
// MFMAs, ONE barrier per step (was two). gemm_voff is 1 block/CU (no TLP
// to hide stalls) so explicit ILP is the right tool. LDS 51.2 -> 81.9 KB.
// ---------------------------------------------------------------------------
__global__ __launch_bounds__(512) void gemm_voff(
    const float* __restrict__ x,
    const __hip_bfloat16* __restrict__ wcatT,
    const float* __restrict__ vbias,
    const float* __restrict__ off_b, const float* __restrict__ attw_b,
    __hip_bfloat16* __restrict__ vb,
    unsigned int* __restrict__ table)
{
  __shared__ short smem[40960];               // 81920 B = 2 x (As 10240 + Bs 30720)
  float (*L)[100] = (float(*)[100])smem;      // aliased AFTER the K loop (51200 B)

  const int t = threadIdx.x;
  const int bid = blockIdx.x;
  // 256 blocks = 8 XCD chunks x 32 tiles; chunk k == batch k
  const int m0 = (((bid & 7) << 5) | (bid >> 3)) * 128;
  const int wave = t >> 6, lane = t & 63, q = lane >> 4, ln = lane & 15;
  const int wm = (wave & 1) * 64, wn = (wave >> 1) * 96;

  f32x4 acc[4][6] = {};

  const int arow = t >> 2, aseg = t & 3;          // A staging: 128 rows x 4 segs
  const float* apg = x + (size_t)(m0 + arow) * 256 + aseg * 8;
  const int adst = arow * 40 + aseg * 8;

  // B staging: 3 16B units per thread, loop-invariant (row, seg)
  int bdst[3];
  const __hip_bfloat16* bsrc[3];
#pragma unroll
  for (int i = 0; i < 3; ++i) {
    int u = t + i * 512, brow = u >> 2, bseg = u & 3;
    bdst[i] = brow * 40 + bseg * 8;
    bsrc[i] = wcatT + (size_t)brow * 256 + bseg * 8;
  }

  // prologue: stage K-step 0 into buffer 0
  float4 fa0 = *(const float4*)(apg);
  float4 fa1 = *(const float4*)(apg + 4);
  int4 br[3];
#pragma unroll
  for (int i = 0; i < 3; ++i) br[i] = *(const int4*)(bsrc[i]);
  {
    alignas(16) __hip_bfloat16 cv[8] = {
      __float2bfloat16(fa0.x), __float2bfloat16(fa0.y), __float2bfloat16(fa0.z), __float2bfloat16(fa0.w),
      __float2bfloat16(fa1.x), __float2bfloat16(fa1.y), __float2bfloat16(fa1.z), __float2bfloat16(fa1.w)};
    *(int4*)&smem[adst] = *(int4*)cv;
#pragma unroll
    for (int i = 0; i < 3; ++i) *(int4*)&smem[5120 + bdst[i]] = br[i];
  }
  __syncthreads();

  int cur = 0;
  for (int k0 = 0; k0 < 256; k0 += 32) {
    const bool haveNext = (k0 < 224);
    // issue next step's global loads NOW — they overlap ds_read + MFMA below
    if (haveNext) {
      fa0 = *(const float4*)(apg + k0 + 32);
      fa1 = *(const float4*)(apg + k0 + 36);
#pragma unroll
      for (int i = 0; i < 3; ++i) br[i] = *(const int4*)(bsrc[i] + k0 + 32);
    }
    const short* As = smem + cur * 20480;
    const short* Bs = As + 5120;
    short8 a[4], b[6];
#pragma unroll
    for (int i = 0; i < 4; ++i) a[i] = *(const short8*)&As[(wm + i * 16 + ln) * 40 + q * 8];
#pragma unroll
    for (int j = 0; j < 6; ++j) b[j] = *(const short8*)&Bs[(wn + j * 16 + ln) * 40 + q * 8];
#pragma unroll
    for (int i = 0; i < 4; ++i)
#pragma unroll
      for (int j = 0; j < 6; ++j)
        acc[i][j] = __builtin_amdgcn_mfma_f32_16x16x32_bf16(a[i], b[j], acc[i][j], 0, 0, 0);
    // write the prefetched tile into the other buffer (vmcnt wait lands here)
    if (haveNext) {
      short* An = smem + (cur ^ 1) * 20480;
      short* Bn = An + 5120;
      alignas(16) __hip_bfloat16 cv[8] = {
        __float2bfloat16(fa0.x), __float2bfloat16(fa0.y), __float2bfloat16(fa0.z), __float2bfloat16(fa0.w),
        __float2bfloat16(fa1.x), __float2bfloat16(fa1.y), __float2bfloat16(fa1.z), __float2bfloat16(fa1.w)};
      *(int4*)&An[adst] = *(int4*)cv;
#pragma unroll
      for (int i = 0; i < 3; ++i) *(int4*)&Bn[bdst[i]] = br[i];
    }
    __syncthreads();                         // ONE barrier per K-step
    cur ^= 1;
  }

  // v outputs + logits to LDS (R7-proven layout: lane holds col=ln, rows q*4+r)
#pragma unroll
  for (int j = 0; j < 6; ++j) {
    int col = wn + j * 16 + ln;
    if (col < 256) {
      float bv = vbias[col];
#pragma unroll
      for (int i = 0; i < 4; ++i) {
        int rowb = m0 + wm + i * 16 + q * 4;
#pragma unroll
        for (int r = 0; r < 4; ++r)
          vb[(size_t)(rowb + r) * 256 + col] = __float2bfloat16(acc[i][j][r] + bv);
      }
    } else if (col < 352) {
      int lc = col - 256;
      float bv = (lc < 64) ? off_b[lc] : attw_b[lc - 64];
#pragma unroll
      for (int i = 0; i < 4; ++i)
#pragma unroll
        for (int r = 0; r < 4; ++r)
          L[wm + i * 16 + q * 4 + r][lc] = acc[i][j][r] + bv;
    }
  }
  __syncthreads();

  // compact table epilogue: 1024 (row,head) pairs, 2 per thread, 24 B each
#pragma unroll
  for (int it = 0; it < 2; ++it) {
    int pl = t + it * 512;
    int rr = pl >> 3, h = pl & 7;
    int row = m0 + rr;

    float a0 = L[rr][64 + h * 4 + 0], a1 = L[rr][64 + h * 4 + 1];
    float a2 = L[rr][64 + h * 4 + 2], a3 = L[rr][64 + h * 4 + 3];
    float mx = fmaxf(fmaxf(a0, a1), fmaxf(a2, a3));
    float e0 = expf(a0 - mx), e1 = expf(a1 - mx), e2 = expf(a2 - mx), e3 = expf(a3 - mx);
    float inv = 1.f / (e0 + e1 + e2 + e3);

    alignas(16) _Float16 pk[12];
#pragma unroll
    for (int p = 0; p < 4; ++p) {
      pk[p * 2 + 0] = (_Float16)(2.f * tanhf(L[rr][h * 8 + p * 2 + 0]));
      pk[p * 2 + 1] = (_Float16)(2.f * tanhf(L[rr][h * 8 + p * 2 + 1]));
    }
    pk[8]  = (_Float16)(e0 * inv);
    pk[9]  = (_Float16)(e1 * inv);
    pk[10] = (_Float16)(e2 * inv);
    pk[11] = (_Float16)(e3 * inv);

    size_t pg = (size_t)row * 8 + h;
    *(uint4*)(table + pg * 8)     = *(uint4*)&pk[0];   // 16 B: dx,dy x4
    *(uint2*)(table + pg * 8 + 4) = *(uint2*)&pk[8];   //  8 B: attn x4
  }
}

// ---------------------------------------------------------------------------
// sampler: thread = (pair, 8-channel group). 64 pairs/block, compact 32 B
// table entries staged in LDS; corners recomputed in-register. Gathers are
// 16B dwordx4 from v. XCD-chunked swizzle: chunk k == batch k on XCD k.
// (unchanged from R7)
// ---------------------------------------------------------------------------
__global__ __launch_bounds__(256) void sample_kernel(
    const __hip_bfloat16* __restrict__ v,
    const unsigned int* __restrict__ table,
    __hip_bfloat16* __restrict__ y)
{
  __shared__ uint4 Tab[128];                 // 64 pairs x 32 B
  const int t = threadIdx.x;
  const int bid = blockIdx.x;
  const int p0 = (((bid & 7) << 9) | (bid >> 3)) * 64;   // batch k on XCD k
  if (t < 128) Tab[t] = *(const uint4*)(table + (size_t)p0 * 8 + t * 4);
  __syncthreads();

  const int g = t & 3, p = t >> 2;
  const int pg = p0 + p;
  const int h = pg & 7;
  const int row = pg >> 3;                   // [0, 32768)
  const int b = row >> 12;
  const int nl = row & (NN - 1);
  const float refx = (float)(nl & 63);
  const float refy = (float)(nl >> 6);

  const _Float16* dp  = (const _Float16*)&Tab[p * 2];      // dx,dy x4
  const _Float16* ap_ = (const _Float16*)&Tab[p * 2 + 1];  // attn x4

  alignas(16) unsigned short idxs[16];
  float ws[16];
#pragma unroll
  for (int pp = 0; pp < 4; ++pp) {
    float gx = refx + (float)dp[2 * pp + 0];
    float gy = refy + (float)dp[2 * pp + 1];
    float x0f = floorf(gx), y0f = floorf(gy);
    int x0 = (int)x0f, y0 = (int)y0f;
    int x1 = x0 + 1,   y1 = y0 + 1;
    float wx1 = gx - x0f, wx0 = 1.f - wx1;
    float wy1 = gy - y0f, wy0 = 1.f - wy1;
    int cx0 = min(max(x0, 0), 63), cx1 = min(max(x1, 0), 63);
    int cy0 = min(max(y0, 0), 63), cy1 = min(max(y1, 0), 63);
    float vx0 = (x0 >= 0 && x0 <= 63) ? 1.f : 0.f;
    float vx1 = (x1 >= 0 && x1 <= 63) ? 1.f : 0.f;
    float vy0 = (y0 >= 0 && y0 <= 63) ? 1.f : 0.f;
    float vy1 = (y1 >= 0 && y1 <= 63) ? 1.f : 0.f;
    float apv = (float)ap_[pp];
    idxs[pp * 4 + 0] = (unsigned short)(cy0 * 64 + cx0);
    idxs[pp * 4 + 1] = (unsigned short)(cy0 * 64 + cx1);
    idxs[pp * 4 + 2] = (unsigned short)(cy1 * 64 + cx0);
    idxs[pp * 4 + 3] = (unsigned short)(cy1 * 64 + cx1);
    ws[pp * 4 + 0] = apv * wx0 * wy0 * vx0 * vy0;
    ws[pp * 4 + 1] = apv * wx1 * wy0 * vx1 * vy0;
    ws[pp * 4 + 2] = apv * wx0 * wy1 * vx0 * vy1;
    ws[pp * 4 + 3] = apv * wx1 * wy1 * vx1 * vy1;
  }

  const char* vbase = (const char*)(v + (size_t)b * NN * 256 + h * 32 + g * 8);

  float acc[8] = {};
#pragma unroll
  for (int j = 0; j < 16; ++j) {
    float w = ws[j];
    int idx = idxs[j];
    int4 pk = *(const int4*)(vbase + (size_t)idx * 512);
    const unsigned short* u = (const unsigned short*)&pk;
#pragma unroll
    for (int c = 0; c < 8; ++c) acc[c] += w * bf2f(u[c]);
  }
  alignas(16) __hip_bfloat16 o[8];
#pragma unroll
  for (int c = 0; c < 8; ++c) o[c] = __float2bfloat16(acc[c]);
  *(int4*)((char*)y + ((size_t)row * 256 + h * 32 + g * 8) * 2) = *(int4*)o;
}

// ---------------------------------------------------------------------------
// proj GEMM: out[M,256] = yb @ pjT^T + proj_b, fp32 out. 64x256 tile, yb
// read once, grid 512 XCD-chunked. (unchanged from R7 — R11's transposed
// epilogue reverted)
// ---------------------------------------------------------------------------
__global__ __launch_bounds__(256) void gemm_proj(
    const short* __restrict__ A, const short* __restrict__ BT,
    const float* __restrict__ bias, float* __restrict__ out)
{
  __shared__ short As[64 * 40];              // 5120 B
  __shared__ short Bs[256 * 40];             // 20480 B
  const int t = threadIdx.x;
  const int bid = blockIdx.x;
  // 512 blocks = 8 chunks x 64 m-tiles; chunk k == batch k
  const int m0 = (((bid & 7) << 6) | (bid >> 3)) * 64;
  const int wave = t >> 6, lane = t & 63, q = lane >> 4, ln = lane & 15;
  const int wn = wave * 64;

  f32x4 acc[4][4] = {};

  const int arow = t >> 2, aseg = t & 3;     // A staging: 64 rows x 4 segs
  const short* apg = A + (size_t)(m0 + arow) * 256 + aseg * 8;

  for (int k0 = 0; k0 < 256; k0 += 32) {
    *(int4*)&As[arow * 40 + aseg * 8] = *(const int4*)(apg + k0);
    // B: 256x32 bf16, 1024 16B units / 256 thr = 4 each
#pragma unroll
    for (int u2 = 0; u2 < 4; ++u2) {
      int c = t + u2 * 256;
      int col = c >> 2, kq = c & 3;
      *(int4*)&Bs[col * 40 + kq * 8] =
          *(const int4*)&BT[(size_t)col * 256 + k0 + kq * 8];
    }
    __syncthreads();
    short8 a[4], b[4];
#pragma unroll
    for (int i = 0; i < 4; ++i) a[i] = *(const short8*)&As[(i * 16 + ln) * 40 + q * 8];
#pragma unroll
    for (int j = 0; j < 4; ++j) b[j] = *(const short8*)&Bs[(wn + j * 16 + ln) * 40 + q * 8];
#pragma unroll
    for (int i = 0; i < 4; ++i)
#pragma unroll
      for (int j = 0; j < 4; ++j)
        acc[i][j] = __builtin_amdgcn_mfma_f32_16x16x32_bf16(a[i], b[j], acc[i][j], 0, 0, 0);
    __syncthreads();
  }

#pragma unroll
  for (int j = 0; j < 4; ++j) {
    int col = wn + j * 16 + ln;
    float bv = bias[col];
#pragma unroll
    for (int i = 0; i < 4; ++i) {
      int rowb = m0 + i * 16 + q * 4;
#pragma unroll
      for (int r = 0; r < 4; ++r)
        out[(size_t)(rowb + r) * 256 + col] = acc[i][j][r] + bv;
    }
  }
}

// ---------------------------------------------------------------------------
extern "C" void kernel_launch(void* const* d_in, const int* in_sizes, int n_in,
                              void* d_out, int out_size, void* d_ws, size_t ws_size,
                              hipStream_t stream) {
  const float* x      = (const float*)d_in[0];
  const float* qkv_w  = (const float*)d_in[1];
  const float* qkv_b  = (const float*)d_in[2];
  const float* off_w  = (const float*)d_in[3];
  const float* off_b  = (const float*)d_in[4];
  const float* attw_w = (const float*)d_in[5];
  const float* attw_b = (const float*)d_in[6];
  const float* proj_w = (const float*)d_in[7];
  const float* proj_b = (const float*)d_in[8];
  float* out = (float*)d_out;

  char* ws = (char*)d_ws;
  __hip_bfloat16* vb    = (__hip_bfloat16*)(ws);                 // 16 MiB
  __hip_bfloat16* yb    = (__hip_bfloat16*)(ws + 16777216);      // 16 MiB
  unsigned int*   table = (unsigned int*)  (ws + 33554432);      // 8 MiB (compact)
  __hip_bfloat16* wcatT = (__hip_bfloat16*)(ws + 41943040);      // 192 KiB
  __hip_bfloat16* pjT   = (__hip_bfloat16*)(ws + 42139648);      // 128 KiB

  cvt_w<<<512, 256, 0, stream>>>(qkv_w, off_w, attw_w, proj_w, wcatT, pjT);
  gemm_voff<<<256, 512, 0, stream>>>(x, wcatT, qkv_b + 512, off_b, attw_b, vb, table);
  sample_kernel<<<4096, 256, 0, stream>>>(vb, table, yb);
  gemm_proj<<<512, 256, 0, stream>>>((const short*)yb, (const short*)pjT, proj_b, out);
}

// Round 17
// 143.060 us; speedup vs baseline: 1.0557x; 1.0003x over previous
//
#include <hip/hip_runtime.h>
#include <hip/hip_bf16.h>
#include <cmath>

#define NN 4096    // H*W
typedef __attribute__((ext_vector_type(8))) short short8;
typedef __attribute__((ext_vector_type(4))) float f32x4;

__device__ __forceinline__ float bf2f(unsigned short u) {
  union { unsigned int i; float f; } c; c.i = ((unsigned int)u) << 16; return c.f;
}

// ---------------------------------------------------------------------------
// weight prep, coalesced reads (c contiguous per k-row), scattered bf16 writes
//   wcatT[c][k] c<256: qkv_w[k][512+c]; c<320: off_w[k][c-256];
//               c<352: attw_w[k][c-320]; else 0
//   pjT[c][k] = proj_w[k][c]
// ---------------------------------------------------------------------------
__global__ __launch_bounds__(256) void cvt_w(
    const float* __restrict__ qkv_w, const float* __restrict__ off_w,
    const float* __restrict__ attw_w, const float* __restrict__ proj_w,
    __hip_bfloat16* __restrict__ wcatT, __hip_bfloat16* __restrict__ pjT)
{
  const int t = threadIdx.x;
  if (blockIdx.x < 256) {
    int k = blockIdx.x;
    wcatT[t * 256 + k] = __float2bfloat16(qkv_w[k * 768 + 512 + t]);
    if (t < 128) {
      int c2 = 256 + t;
      float v = 0.f;
      if (c2 < 320)      v = off_w[k * 64 + (c2 - 256)];
      else if (c2 < 352) v = attw_w[k * 32 + (c2 - 320)];
      wcatT[c2 * 256 + k] = __float2bfloat16(v);
    }
  } else {
    int k = blockIdx.x - 256;
    pjT[t * 256 + k] = __float2bfloat16(proj_w[k * 256 + t]);
  }
}

// ---------------------------------------------------------------------------
// fused v-GEMM + offset/attention logits + COMPACT sampling-table epilogue.
// R14-measured base (143.1 us). SINGLE CHANGE vs R14: v-write via LDS BOUNCE
// — acc+bias staged to padded Vs[128][264] (528 B row stride: 2-way bank
// aliasing only, free per m136), then 8 fully-coalesced dwordx4 passes to
// vb (1 KB/wave-instr). Replaces 96 scattered scalar stores/thread with 8
// coalesced ones. R11 proved epilogue store shape is worth ~8.5 us; this
// fixes it in the direction of better coalescing (R11 went worse).
// ---------------------------------------------------------------------------
__global__ __launch_bounds__(512) void gemm_voff(
    const float* __restrict__ x,
    const __hip_bfloat16* __restrict__ wcatT,
    const float* __restrict__ vbias,
    const float* __restrict__ off_b, const float* __restrict__ attw_b,
    __hip_bfloat16* __restrict__ vb,
    unsigned int* __restrict__ table)
{
  __shared__ short smem[40960];               // 81920 B = 2 x (As 10240 + Bs 30720)
  float (*L)[100] = (float(*)[100])smem;      // logits alias (51200 B), after v-store
  __hip_bfloat16 (*Vs)[264] = (__hip_bfloat16(*)[264])smem;  // 67584 B v-stage alias

  const int t = threadIdx.x;
  const int bid = blockIdx.x;
  // 256 blocks = 8 XCD chunks x 32 tiles; chunk k == batch k
  const int m0 = (((bid & 7) << 5) | (bid >> 3)) * 128;
  const int wave = t >> 6, lane = t & 63, q = lane >> 4, ln = lane & 15;
  const int wm = (wave & 1) * 64, wn = (wave >> 1) * 96;

  f32x4 acc[4][6] = {};

  const int arow = t >> 2, aseg = t & 3;          // A staging: 128 rows x 4 segs
  const float* apg = x + (size_t)(m0 + arow) * 256 + aseg * 8;
  const int adst = arow * 40 + aseg * 8;

  // B staging: 3 16B units per thread, loop-invariant (row, seg)
  int bdst[3];
  const __hip_bfloat16* bsrc[3];
#pragma unroll
  for (int i = 0; i < 3; ++i) {
    int u = t + i * 512, brow = u >> 2, bseg = u & 3;
    bdst[i] = brow * 40 + bseg * 8;
    bsrc[i] = wcatT + (size_t)brow * 256 + bseg * 8;
  }

  // prologue: stage K-step 0 into buffer 0
  float4 fa0 = *(const float4*)(apg);
  float4 fa1 = *(const float4*)(apg + 4);
  int4 br[3];
#pragma unroll
  for (int i = 0; i < 3; ++i) br[i] = *(const int4*)(bsrc[i]);
  {
    alignas(16) __hip_bfloat16 cv[8] = {
      __float2bfloat16(fa0.x), __float2bfloat16(fa0.y), __float2bfloat16(fa0.z), __float2bfloat16(fa0.w),
      __float2bfloat16(fa1.x), __float2bfloat16(fa1.y), __float2bfloat16(fa1.z), __float2bfloat16(fa1.w)};
    *(int4*)&smem[adst] = *(int4*)cv;
#pragma unroll
    for (int i = 0; i < 3; ++i) *(int4*)&smem[5120 + bdst[i]] = br[i];
  }
  __syncthreads();

  int cur = 0;
  for (int k0 = 0; k0 < 256; k0 += 32) {
    const bool haveNext = (k0 < 224);
    // issue next step's global loads NOW — they overlap ds_read + MFMA below
    if (haveNext) {
      fa0 = *(const float4*)(apg + k0 + 32);
      fa1 = *(const float4*)(apg + k0 + 36);
#pragma unroll
      for (int i = 0; i < 3; ++i) br[i] = *(const int4*)(bsrc[i] + k0 + 32);
    }
    const short* As = smem + cur * 20480;
    const short* Bs = As + 5120;
    short8 a[4], b[6];
#pragma unroll
    for (int i = 0; i < 4; ++i) a[i] = *(const short8*)&As[(wm + i * 16 + ln) * 40 + q * 8];
#pragma unroll
    for (int j = 0; j < 6; ++j) b[j] = *(const short8*)&Bs[(wn + j * 16 + ln) * 40 + q * 8];
#pragma unroll
    for (int i = 0; i < 4; ++i)
#pragma unroll
      for (int j = 0; j < 6; ++j)
        acc[i][j] = __builtin_amdgcn_mfma_f32_16x16x32_bf16(a[i], b[j], acc[i][j], 0, 0, 0);
    // write the prefetched tile into the other buffer (vmcnt wait lands here)
    if (haveNext) {
      short* An = smem + (cur ^ 1) * 20480;
      short* Bn = An + 5120;
      alignas(16) __hip_bfloat16 cv[8] = {
        __float2bfloat16(fa0.x), __float2bfloat16(fa0.y), __float2bfloat16(fa0.z), __float2bfloat16(fa0.w),
        __float2bfloat16(fa1.x), __float2bfloat16(fa1.y), __float2bfloat16(fa1.z), __float2bfloat16(fa1.w)};
      *(int4*)&An[adst] = *(int4*)cv;
#pragma unroll
      for (int i = 0; i < 3; ++i) *(int4*)&Bn[bdst[i]] = br[i];
    }
    __syncthreads();                         // ONE barrier per K-step
    cur ^= 1;
  }

  // ---- v epilogue via LDS bounce: stage acc+bias, then coalesced stores ----
#pragma unroll
  for (int j = 0; j < 6; ++j) {
    int col = wn + j * 16 + ln;
    if (col < 256) {
      float bv = vbias[col];
#pragma unroll
      for (int i = 0; i < 4; ++i) {
        int rr = wm + i * 16 + q * 4;
#pragma unroll
        for (int r = 0; r < 4; ++r)
          Vs[rr + r][col] = __float2bfloat16(acc[i][j][r] + bv);
      }
    }
  }
  __syncthreads();
  {
    const int rowp = t >> 5, cseg = (t & 31) * 8;    // 16 rows/pass, 16 B segs
#pragma unroll
    for (int pass = 0; pass < 8; ++pass) {
      int rr = pass * 16 + rowp;
      *(int4*)&vb[(size_t)(m0 + rr) * 256 + cseg] = *(int4*)&Vs[rr][cseg];
    }
  }
  __syncthreads();

  // logits to L (aliases Vs region — safe after the barrier above)
#pragma unroll
  for (int j = 0; j < 6; ++j) {
    int col = wn + j * 16 + ln;
    if (col >= 256 && col < 352) {
      int lc = col - 256;
      float bv = (lc < 64) ? off_b[lc] : attw_b[lc - 64];
#pragma unroll
      for (int i = 0; i < 4; ++i)
#pragma unroll
        for (int r = 0; r < 4; ++r)
          L[wm + i * 16 + q * 4 + r][lc] = acc[i][j][r] + bv;
    }
  }
  __syncthreads();

  // compact table epilogue: 1024 (row,head) pairs, 2 per thread, 24 B each
#pragma unroll
  for (int it = 0; it < 2; ++it) {
    int pl = t + it * 512;
    int rr = pl >> 3, h = pl & 7;
    int row = m0 + rr;

    float a0 = L[rr][64 + h * 4 + 0], a1 = L[rr][64 + h * 4 + 1];
    float a2 = L[rr][64 + h * 4 + 2], a3 = L[rr][64 + h * 4 + 3];
    float mx = fmaxf(fmaxf(a0, a1), fmaxf(a2, a3));
    float e0 = expf(a0 - mx), e1 = expf(a1 - mx), e2 = expf(a2 - mx), e3 = expf(a3 - mx);
    float inv = 1.f / (e0 + e1 + e2 + e3);

    alignas(16) _Float16 pk[12];
#pragma unroll
    for (int p = 0; p < 4; ++p) {
      pk[p * 2 + 0] = (_Float16)(2.f * tanhf(L[rr][h * 8 + p * 2 + 0]));
      pk[p * 2 + 1] = (_Float16)(2.f * tanhf(L[rr][h * 8 + p * 2 + 1]));
    }
    pk[8]  = (_Float16)(e0 * inv);
    pk[9]  = (_Float16)(e1 * inv);
    pk[10] = (_Float16)(e2 * inv);
    pk[11] = (_Float16)(e3 * inv);

    size_t pg = (size_t)row * 8 + h;
    *(uint4*)(table + pg * 8)     = *(uint4*)&pk[0];   // 16 B: dx,dy x4
    *(uint2*)(table + pg * 8 + 4) = *(uint2*)&pk[8];   //  8 B: attn x4
  }
}

// ---------------------------------------------------------------------------
// sampler: thread = (pair, 8-channel group). 64 pairs/block, compact 32 B
// table entries staged in LDS; corners recomputed in-register. Gathers are
// 16B dwordx4 from v. XCD-chunked swizzle: chunk k == batch k on XCD k.
// (unchanged from R7)
// ---------------------------------------------------------------------------
__global__ __launch_bounds__(256) void sample_kernel(
    const __hip_bfloat16* __restrict__ v,
    const unsigned int* __restrict__ table,
    __hip_bfloat16* __restrict__ y)
{
  __shared__ uint4 Tab[128];                 // 64 pairs x 32 B
  const int t = threadIdx.x;
  const int bid = blockIdx.x;
  const int p0 = (((bid & 7) << 9) | (bid >> 3)) * 64;   // batch k on XCD k
  if (t < 128) Tab[t] = *(const uint4*)(table + (size_t)p0 * 8 + t * 4);
  __syncthreads();

  const int g = t & 3, p = t >> 2;
  const int pg = p0 + p;
  const int h = pg & 7;
  const int row = pg >> 3;                   // [0, 32768)
  const int b = row >> 12;
  const int nl = row & (NN - 1);
  const float refx = (float)(nl & 63);
  const float refy = (float)(nl >> 6);

  const _Float16* dp  = (const _Float16*)&Tab[p * 2];      // dx,dy x4
  const _Float16* ap_ = (const _Float16*)&Tab[p * 2 + 1];  // attn x4

  alignas(16) unsigned short idxs[16];
  float ws[16];
#pragma unroll
  for (int pp = 0; pp < 4; ++pp) {
    float gx = refx + (float)dp[2 * pp + 0];
    float gy = refy + (float)dp[2 * pp + 1];
    float x0f = floorf(gx), y0f = floorf(gy);
    int x0 = (int)x0f, y0 = (int)y0f;
    int x1 = x0 + 1,   y1 = y0 + 1;
    float wx1 = gx - x0f, wx0 = 1.f - wx1;
    float wy1 = gy - y0f, wy0 = 1.f - wy1;
    int cx0 = min(max(x0, 0), 63), cx1 = min(max(x1, 0), 63);
    int cy0 = min(max(y0, 0), 63), cy1 = min(max(y1, 0), 63);
    float vx0 = (x0 >= 0 && x0 <= 63) ? 1.f : 0.f;
    float vx1 = (x1 >= 0 && x1 <= 63) ? 1.f : 0.f;
    float vy0 = (y0 >= 0 && y0 <= 63) ? 1.f : 0.f;
    float vy1 = (y1 >= 0 && y1 <= 63) ? 1.f : 0.f;
    float apv = (float)ap_[pp];
    idxs[pp * 4 + 0] = (unsigned short)(cy0 * 64 + cx0);
    idxs[pp * 4 + 1] = (unsigned short)(cy0 * 64 + cx1);
    idxs[pp * 4 + 2] = (unsigned short)(cy1 * 64 + cx0);
    idxs[pp * 4 + 3] = (unsigned short)(cy1 * 64 + cx1);
    ws[pp * 4 + 0] = apv * wx0 * wy0 * vx0 * vy0;
    ws[pp * 4 + 1] = apv * wx1 * wy0 * vx1 * vy0;
    ws[pp * 4 + 2] = apv * wx0 * wy1 * vx0 * vy1;
    ws[pp * 4 + 3] = apv * wx1 * wy1 * vx1 * vy1;
  }

  const char* vbase = (const char*)(v + (size_t)b * NN * 256 + h * 32 + g * 8);

  float acc[8] = {};
#pragma unroll
  for (int j = 0; j < 16; ++j) {
    float w = ws[j];
    int idx = idxs[j];
    int4 pk = *(const int4*)(vbase + (size_t)idx * 512);
    const unsigned short* u = (const unsigned short*)&pk;
#pragma unroll
    for (int c = 0; c < 8; ++c) acc[c] += w * bf2f(u[c]);
  }
  alignas(16) __hip_bfloat16 o[8];
#pragma unroll
  for (int c = 0; c < 8; ++c) o[c] = __float2bfloat16(acc[c]);
  *(int4*)((char*)y + ((size_t)row * 256 + h * 32 + g * 8) * 2) = *(int4*)o;
}

// ---------------------------------------------------------------------------
// proj GEMM: out[M,256] = yb @ pjT^T + proj_b, fp32 out. 64x256 tile, yb
// read once, grid 512 XCD-chunked. (unchanged from R7)
// ---------------------------------------------------------------------------
__global__ __launch_bounds__(256) void gemm_proj(
    const short* __restrict__ A, const short* __restrict__ BT,
    const float* __restrict__ bias, float* __restrict__ out)
{
  __shared__ short As[64 * 40];              // 5120 B
  __shared__ short Bs[256 * 40];             // 20480 B
  const int t = threadIdx.x;
  const int bid = blockIdx.x;
  // 512 blocks = 8 chunks x 64 m-tiles; chunk k == batch k
  const int m0 = (((bid & 7) << 6) | (bid >> 3)) * 64;
  const int wave = t >> 6, lane = t & 63, q = lane >> 4, ln = lane & 15;
  const int wn = wave * 64;

  f32x4 acc[4][4] = {};

  const int arow = t >> 2, aseg = t & 3;     // A staging: 64 rows x 4 segs
  const short* apg = A + (size_t)(m0 + arow) * 256 + aseg * 8;

  for (int k0 = 0; k0 < 256; k0 += 32) {
    *(int4*)&As[arow * 40 + aseg * 8] = *(const int4*)(apg + k0);
    // B: 256x32 bf16, 1024 16B units / 256 thr = 4 each
#pragma unroll
    for (int u2 = 0; u2 < 4; ++u2) {
      int c = t + u2 * 256;
      int col = c >> 2, kq = c & 3;
      *(int4*)&Bs[col * 40 + kq * 8] =
          *(const int4*)&BT[(size_t)col * 256 + k0 + kq * 8];
    }
    __syncthreads();
    short8 a[4], b[4];
#pragma unroll
    for (int i = 0; i < 4; ++i) a[i] = *(const short8*)&As[(i * 16 + ln) * 40 + q * 8];
#pragma unroll
    for (int j = 0; j < 4; ++j) b[j] = *(const short8*)&Bs[(wn + j * 16 + ln) * 40 + q * 8];
#pragma unroll
    for (int i = 0; i < 4; ++i)
#pragma unroll
      for (int j = 0; j < 4; ++j)
        acc[i][j] = __builtin_amdgcn_mfma_f32_16x16x32_bf16(a[i], b[j], acc[i][j], 0, 0, 0);
    __syncthreads();
  }

#pragma unroll
  for (int j = 0; j < 4; ++j) {
    int col = wn + j * 16 + ln;
    float bv = bias[col];
#pragma unroll
    for (int i = 0; i < 4; ++i) {
      int rowb = m0 + i * 16 + q * 4;
#pragma unroll
      for (int r = 0; r < 4; ++r)
        out[(size_t)(rowb + r) * 256 + col] = acc[i][j][r] + bv;
    }
  }
}

// ---------------------------------------------------------------------------
extern "C" void kernel_launch(void* const* d_in, const int* in_sizes, int n_in,
                              void* d_out, int out_size, void* d_ws, size_t ws_size,
                              hipStream_t stream) {
  const float* x      = (const float*)d_in[0];
  const float* qkv_w  = (const float*)d_in[1];
  const float* qkv_b  = (const float*)d_in[2];
  const float* off_w  = (const float*)d_in[3];
  const float* off_b  = (const float*)d_in[4];
  const float* attw_w = (const float*)d_in[5];
  const float* attw_b = (const float*)d_in[6];
  const float* proj_w = (const float*)d_in[7];
  const float* proj_b = (const float*)d_in[8];
  float* out = (float*)d_out;

  char* ws = (char*)d_ws;
  __hip_bfloat16* vb    = (__hip_bfloat16*)(ws);                 // 16 MiB
  __hip_bfloat16* yb    = (__hip_bfloat16*)(ws + 16777216);      // 16 MiB
  unsigned int*   table = (unsigned int*)  (ws + 33554432);      // 8 MiB (compact)
  __hip_bfloat16* wcatT = (__hip_bfloat16*)(ws + 41943040);      // 192 KiB
  __hip_bfloat16* pjT   = (__hip_bfloat16*)(ws + 42139648);      // 128 KiB

  cvt_w<<<512, 256, 0, stream>>>(qkv_w, off_w, attw_w, proj_w, wcatT, pjT);
  gemm_voff<<<256, 512, 0, stream>>>(x, wcatT, qkv_b + 512, off_b, attw_b, vb, table);
  sample_kernel<<<4096, 256, 0, stream>>>(vb, table, yb);
  gemm_proj<<<512, 256, 0, stream>>>((const short*)yb, (const short*)pjT, proj_b, out);
}